// Round 1
// baseline (309.185 us; speedup 1.0000x reference)
//
#include <hip/hip_runtime.h>

#define BATCH  16384
#define NF     26
#define ND     13
#define NE     16
#define V1     100001
#define H1     128
#define H2     64
#define IN_DIM 429     // NF*NE + ND
#define KPAD   448     // 14 * 32
#define EPS    1e-5f

#define BM     32      // rows per block
#define SD     456     // deepS row stride (ushort): 456*2=912B, 912%16==0, 228 dwords %32 = 4 -> conflict-free-ish
#define SH     136     // h1S row stride (ushort): 272B, 68 dwords %32 = 4

typedef __attribute__((ext_vector_type(8))) short short8;
typedef __attribute__((ext_vector_type(4))) float f32x4;

static __device__ __forceinline__ unsigned short f2bf(float x) {
    unsigned int u = __float_as_uint(x);
    unsigned int r = (u + 0x7FFFu + ((u >> 16) & 1u)) >> 16;   // RNE
    return (unsigned short)r;
}
static __device__ __forceinline__ float bf2f(unsigned short s) {
    return __uint_as_float(((unsigned int)s) << 16);
}

// ---------------------------------------------------------------------------
// Prep kernel: fold BN into effective weights, pack into MFMA B-fragment order.
// packB1: [nblk(8)][ks(14)][lane(64)][8 bf16]  B[k][col], col=16*nblk+(l&15), k=32*ks+(l>>4)*8+j
// packB2: [nblk(4)][ks(4)] [lane(64)][8 bf16]
// ---------------------------------------------------------------------------
__global__ __launch_bounds__(256) void prep_kernel(
    const float* __restrict__ bn0_g, const float* __restrict__ bn0_b,
    const float* __restrict__ bn0_m, const float* __restrict__ bn0_v,
    const float* __restrict__ W1,    const float* __restrict__ b1,
    const float* __restrict__ bn1_g, const float* __restrict__ bn1_b,
    const float* __restrict__ bn1_m, const float* __restrict__ bn1_v,
    const float* __restrict__ W2,    const float* __restrict__ b2,
    const float* __restrict__ bn2_g, const float* __restrict__ bn2_b,
    const float* __restrict__ bn2_m, const float* __restrict__ bn2_v,
    const float* __restrict__ bo,    const float* __restrict__ gbias,
    const float* __restrict__ ldb,
    unsigned short* __restrict__ packB1, unsigned short* __restrict__ packB2,
    float* __restrict__ ceff, float* __restrict__ c2, float* __restrict__ constv)
{
    const int blk = blockIdx.x, tid = threadIdx.x;

    if (blk < 28) {                       // packB1: 7168 threads
        int t    = blk * 256 + tid;
        int nblk = t / (14 * 64);
        int rem  = t % (14 * 64);
        int ks   = rem >> 6;
        int l    = rem & 63;
        int col  = nblk * 16 + (l & 15);
        float a1 = bn1_g[col] * rsqrtf(bn1_v[col] + EPS);
        int k0   = ks * 32 + ((l >> 4) << 3);
        union { short8 v; unsigned short u[8]; } tmp;
        #pragma unroll
        for (int j = 0; j < 8; ++j) {
            int k = k0 + j;
            float v = 0.f;
            if (k < IN_DIM) {
                float a0 = bn0_g[k] * rsqrtf(bn0_v[k] + EPS);
                v = W1[col * IN_DIM + k] * a0 * a1;
            }
            tmp.u[j] = f2bf(v);
        }
        *reinterpret_cast<short8*>(packB1 + (size_t)t * 8) = tmp.v;
    } else if (blk < 32) {                // packB2: 1024 threads
        int t    = (blk - 28) * 256 + tid;
        int nblk = t >> 8;
        int rem  = t & 255;
        int ks   = rem >> 6;
        int l    = rem & 63;
        int col  = nblk * 16 + (l & 15);
        float a2 = bn2_g[col] * rsqrtf(bn2_v[col] + EPS);
        int k0   = ks * 32 + ((l >> 4) << 3);
        union { short8 v; unsigned short u[8]; } tmp;
        #pragma unroll
        for (int j = 0; j < 8; ++j) {
            int k = k0 + j;
            tmp.u[j] = f2bf(W2[col * H1 + k] * a2);
        }
        *reinterpret_cast<short8*>(packB2 + (size_t)t * 8) = tmp.v;
    } else if (blk == 32) {               // ceff[128]: wave-per-o-group
        int w = tid >> 6, l = tid & 63;
        for (int o = w; o < H1; o += 4) {
            float sum = 0.f;
            #pragma unroll
            for (int i = 0; i < 7; ++i) {
                int k = l + i * 64;
                if (k < IN_DIM) {
                    float a0 = bn0_g[k] * rsqrtf(bn0_v[k] + EPS);
                    float u0 = bn0_b[k] - a0 * bn0_m[k];
                    sum += u0 * W1[o * IN_DIM + k];
                }
            }
            sum += __shfl_xor(sum, 32);
            sum += __shfl_xor(sum, 16);
            sum += __shfl_xor(sum, 8);
            sum += __shfl_xor(sum, 4);
            sum += __shfl_xor(sum, 2);
            sum += __shfl_xor(sum, 1);
            if (l == 0) {
                float a1 = bn1_g[o] * rsqrtf(bn1_v[o] + EPS);
                ceff[o] = a1 * (sum + b1[o] - bn1_m[o]) + bn1_b[o];
            }
        }
    } else {                              // c2[64] + fused constant
        if (tid < H2) {
            float a2 = bn2_g[tid] * rsqrtf(bn2_v[tid] + EPS);
            c2[tid] = a2 * (b2[tid] - bn2_m[tid]) + bn2_b[tid];
        } else if (tid == 64) {
            constv[0] = gbias[0] + bo[0] + ldb[0];
        }
    }
}

// ---------------------------------------------------------------------------
// Main fused kernel: gather + FM + linear + MLP (2 MFMA GEMMs) + combine.
// 512 blocks x 256 threads, 32 rows/block.
// ---------------------------------------------------------------------------
__global__ __launch_bounds__(256) void deepfm_main(
    const int*   __restrict__ sparse, const float* __restrict__ dense,
    const float* __restrict__ emb,    const float* __restrict__ lin,
    const float* __restrict__ ldw,
    const unsigned short* __restrict__ packB1,
    const unsigned short* __restrict__ packB2,
    const float* __restrict__ ceff, const float* __restrict__ c2w,
    const float* __restrict__ Wo,   const float* __restrict__ constv,
    float* __restrict__ out)
{
    __shared__ __align__(16) unsigned short deepS[BM][SD];
    __shared__ __align__(16) unsigned short h1S[BM][SH];
    __shared__ float accS[BM];

    const int tid = threadIdx.x;
    const int r0  = blockIdx.x * BM;

    // Phase A: init accumulators + zero K-padding (cols 429..447)
    if (tid < BM) accS[tid] = constv[0];
    for (int z = tid; z < BM * (KPAD - IN_DIM); z += 256) {
        int row = z / (KPAD - IN_DIM);
        int c   = IN_DIM + z % (KPAD - IN_DIM);
        deepS[row][c] = 0;
    }
    __syncthreads();

    // Phase B: embedding gather (4 lanes per (row,feature); 16B each) + linear_sparse
    #pragma unroll
    for (int it = 0; it < 13; ++it) {                 // 32*26*4 / 256 = 13
        int q = tid + it * 256;
        int p = q >> 2, quarter = q & 3;
        int row = p / NF, f = p - row * NF;
        int idx = sparse[(r0 + row) * NF + f];
        const float* src = emb + ((size_t)f * V1 + (size_t)idx) * NE + quarter * 4;
        float4 v = *reinterpret_cast<const float4*>(src);
        ushort4 sv = { f2bf(v.x), f2bf(v.y), f2bf(v.z), f2bf(v.w) };
        *reinterpret_cast<ushort4*>(&deepS[row][f * NE + quarter * 4]) = sv;
        if (quarter == 0) {
            atomicAdd(&accS[row], lin[(size_t)f * V1 + (size_t)idx]);
        }
    }
    // Phase C: dense features + linear_dense
    for (int t = tid; t < BM * ND; t += 256) {
        int row = t / ND, j = t - row * ND;
        float v = dense[(r0 + row) * ND + j];
        deepS[row][NF * NE + j] = f2bf(v);
        atomicAdd(&accS[row], v * ldw[j]);
    }
    __syncthreads();

    // Phase D: FM term (fp32 accumulation from bf16 tile)
    for (int t = tid; t < BM * NE; t += 256) {
        int row = t >> 4, e = t & 15;
        float s = 0.f, ss = 0.f;
        #pragma unroll
        for (int f = 0; f < NF; ++f) {
            float x = bf2f(deepS[row][f * NE + e]);
            s += x; ss += x * x;
        }
        atomicAdd(&accS[row], 0.5f * (s * s - ss));
    }

    // Phase E: GEMM1 [32 x 448] x [448 -> 128] via mfma 16x16x32 bf16
    const int w = tid >> 6, l = tid & 63;
    const int mblk = w & 1, nset = w >> 1;
    const int lr = l & 15, lq = l >> 4;

    f32x4 acc1[4] = { {0.f,0.f,0.f,0.f}, {0.f,0.f,0.f,0.f},
                      {0.f,0.f,0.f,0.f}, {0.f,0.f,0.f,0.f} };
    const short8* pB1 = reinterpret_cast<const short8*>(packB1);
    #pragma unroll
    for (int ks = 0; ks < KPAD / 32; ++ks) {
        short8 aF = *reinterpret_cast<const short8*>(&deepS[mblk * 16 + lr][ks * 32 + lq * 8]);
        #pragma unroll
        for (int nb = 0; nb < 4; ++nb) {
            int nblk = nset * 4 + nb;
            short8 bF = pB1[((size_t)nblk * 14 + ks) * 64 + l];
            acc1[nb] = __builtin_amdgcn_mfma_f32_16x16x32_bf16(aF, bF, acc1[nb], 0, 0, 0);
        }
    }
    // Epilogue 1: +ceff, relu, -> bf16 LDS (C/D layout: col=l&15, row=lq*4+r)
    #pragma unroll
    for (int nb = 0; nb < 4; ++nb) {
        int col = (nset * 4 + nb) * 16 + lr;
        float ce = ceff[col];
        #pragma unroll
        for (int r = 0; r < 4; ++r) {
            float h = fmaxf(acc1[nb][r] + ce, 0.f);
            h1S[mblk * 16 + lq * 4 + r][col] = f2bf(h);
        }
    }
    __syncthreads();

    // Phase F: GEMM2 [32 x 128] x [128 -> 64]
    f32x4 acc2[2] = { {0.f,0.f,0.f,0.f}, {0.f,0.f,0.f,0.f} };
    const short8* pB2 = reinterpret_cast<const short8*>(packB2);
    #pragma unroll
    for (int ks = 0; ks < 4; ++ks) {
        short8 aF = *reinterpret_cast<const short8*>(&h1S[mblk * 16 + lr][ks * 32 + lq * 8]);
        #pragma unroll
        for (int nb = 0; nb < 2; ++nb) {
            int nblk = nset * 2 + nb;
            short8 bF = pB2[((size_t)nblk * 4 + ks) * 64 + l];
            acc2[nb] = __builtin_amdgcn_mfma_f32_16x16x32_bf16(aF, bF, acc2[nb], 0, 0, 0);
        }
    }
    // Epilogue 2: +c2, relu, dot with Wo, reduce over cols, add to accS
    float part[4] = { 0.f, 0.f, 0.f, 0.f };
    #pragma unroll
    for (int nb = 0; nb < 2; ++nb) {
        int col = (nset * 2 + nb) * 16 + lr;
        float cv = c2w[col], wv = Wo[col];
        #pragma unroll
        for (int r = 0; r < 4; ++r) {
            float h = fmaxf(acc2[nb][r] + cv, 0.f);
            part[r] = fmaf(h, wv, part[r]);
        }
    }
    #pragma unroll
    for (int r = 0; r < 4; ++r) {
        part[r] += __shfl_xor(part[r], 1);
        part[r] += __shfl_xor(part[r], 2);
        part[r] += __shfl_xor(part[r], 4);
        part[r] += __shfl_xor(part[r], 8);
    }
    if (lr == 0) {
        #pragma unroll
        for (int r = 0; r < 4; ++r)
            atomicAdd(&accS[mblk * 16 + lq * 4 + r], part[r]);
    }
    __syncthreads();

    // Phase G: write outputs
    if (tid < BM) out[r0 + tid] = accS[tid];
}

extern "C" void kernel_launch(void* const* d_in, const int* in_sizes, int n_in,
                              void* d_out, int out_size, void* d_ws, size_t ws_size,
                              hipStream_t stream) {
    const int*   sparse = (const int*)d_in[0];
    const float* dense  = (const float*)d_in[1];
    const float* emb    = (const float*)d_in[2];
    const float* lin    = (const float*)d_in[3];
    const float* ldw    = (const float*)d_in[4];
    const float* ldb    = (const float*)d_in[5];
    const float* bn0g = (const float*)d_in[6],  *bn0b = (const float*)d_in[7];
    const float* bn0m = (const float*)d_in[8],  *bn0v = (const float*)d_in[9];
    const float* W1   = (const float*)d_in[10], *b1   = (const float*)d_in[11];
    const float* bn1g = (const float*)d_in[12], *bn1b = (const float*)d_in[13];
    const float* bn1m = (const float*)d_in[14], *bn1v = (const float*)d_in[15];
    const float* W2   = (const float*)d_in[16], *b2   = (const float*)d_in[17];
    const float* bn2g = (const float*)d_in[18], *bn2b = (const float*)d_in[19];
    const float* bn2m = (const float*)d_in[20], *bn2v = (const float*)d_in[21];
    const float* Wo   = (const float*)d_in[22], *bo   = (const float*)d_in[23];
    const float* gbias = (const float*)d_in[24];

    char* ws = (char*)d_ws;
    unsigned short* packB1 = (unsigned short*)ws;              // 114688 B
    unsigned short* packB2 = (unsigned short*)(ws + 114688);   //  16384 B
    float* ceff   = (float*)(ws + 131072);                     //    512 B
    float* c2     = (float*)(ws + 131584);                     //    256 B
    float* constv = (float*)(ws + 131840);                     //      4 B

    prep_kernel<<<34, 256, 0, stream>>>(
        bn0g, bn0b, bn0m, bn0v, W1, b1, bn1g, bn1b, bn1m, bn1v,
        W2, b2, bn2g, bn2b, bn2m, bn2v, bo, gbias, ldb,
        packB1, packB2, ceff, c2, constv);

    deepfm_main<<<BATCH / BM, 256, 0, stream>>>(
        sparse, dense, emb, lin, ldw, packB1, packB2, ceff, c2, Wo, constv,
        (float*)d_out);
}

// Round 2
// 272.491 us; speedup vs baseline: 1.1347x; 1.1347x over previous
//
#include <hip/hip_runtime.h>

#define BATCH  16384
#define NF     26
#define ND     13
#define NE     16
#define V1     100001
#define H1     128
#define H2     64
#define IN_DIM 429     // NF*NE + ND
#define KPAD   448     // 14 * 32
#define EPS    1e-5f

#define BM     32      // rows per block
#define NT     512     // threads per block (8 waves)
#define SD     456     // deepS row stride (ushort): 912B/row, %16==0, 228 dwords %32 = 4
#define SH     136     // h1S row stride (ushort)

typedef __attribute__((ext_vector_type(8))) short short8;
typedef __attribute__((ext_vector_type(4))) float f32x4;

static __device__ __forceinline__ unsigned short f2bf(float x) {
    unsigned int u = __float_as_uint(x);
    unsigned int r = (u + 0x7FFFu + ((u >> 16) & 1u)) >> 16;   // RNE
    return (unsigned short)r;
}
static __device__ __forceinline__ float bf2f(unsigned short s) {
    return __uint_as_float(((unsigned int)s) << 16);
}

// ---------------------------------------------------------------------------
// Prep kernel: fold BN into effective weights, pack into MFMA B-fragment order.
// packB1: [nblk(8)][ks(14)][lane(64)][8 bf16]  B[k][col], col=16*nblk+(l&15), k=32*ks+(l>>4)*8+j
// packB2: [nblk(4)][ks(4)] [lane(64)][8 bf16]
// Grid: 0-27 packB1, 28-31 packB2, 32-39 ceff (parallelized), 40 c2+const.
// ---------------------------------------------------------------------------
__global__ __launch_bounds__(256) void prep_kernel(
    const float* __restrict__ bn0_g, const float* __restrict__ bn0_b,
    const float* __restrict__ bn0_m, const float* __restrict__ bn0_v,
    const float* __restrict__ W1,    const float* __restrict__ b1,
    const float* __restrict__ bn1_g, const float* __restrict__ bn1_b,
    const float* __restrict__ bn1_m, const float* __restrict__ bn1_v,
    const float* __restrict__ W2,    const float* __restrict__ b2,
    const float* __restrict__ bn2_g, const float* __restrict__ bn2_b,
    const float* __restrict__ bn2_m, const float* __restrict__ bn2_v,
    const float* __restrict__ bo,    const float* __restrict__ gbias,
    const float* __restrict__ ldb,
    unsigned short* __restrict__ packB1, unsigned short* __restrict__ packB2,
    float* __restrict__ ceff, float* __restrict__ c2, float* __restrict__ constv)
{
    const int blk = blockIdx.x, tid = threadIdx.x;

    if (blk < 28) {                       // packB1: 7168 threads
        int t    = blk * 256 + tid;
        int nblk = t / (14 * 64);
        int rem  = t % (14 * 64);
        int ks   = rem >> 6;
        int l    = rem & 63;
        int col  = nblk * 16 + (l & 15);
        float a1 = bn1_g[col] * rsqrtf(bn1_v[col] + EPS);
        int k0   = ks * 32 + ((l >> 4) << 3);
        union { short8 v; unsigned short u[8]; } tmp;
        #pragma unroll
        for (int j = 0; j < 8; ++j) {
            int k = k0 + j;
            float v = 0.f;
            if (k < IN_DIM) {
                float a0 = bn0_g[k] * rsqrtf(bn0_v[k] + EPS);
                v = W1[col * IN_DIM + k] * a0 * a1;
            }
            tmp.u[j] = f2bf(v);
        }
        *reinterpret_cast<short8*>(packB1 + (size_t)t * 8) = tmp.v;
    } else if (blk < 32) {                // packB2: 1024 threads
        int t    = (blk - 28) * 256 + tid;
        int nblk = t >> 8;
        int rem  = t & 255;
        int ks   = rem >> 6;
        int l    = rem & 63;
        int col  = nblk * 16 + (l & 15);
        float a2 = bn2_g[col] * rsqrtf(bn2_v[col] + EPS);
        int k0   = ks * 32 + ((l >> 4) << 3);
        union { short8 v; unsigned short u[8]; } tmp;
        #pragma unroll
        for (int j = 0; j < 8; ++j) {
            int k = k0 + j;
            tmp.u[j] = f2bf(W2[col * H1 + k] * a2);
        }
        *reinterpret_cast<short8*>(packB2 + (size_t)t * 8) = tmp.v;
    } else if (blk < 40) {                // ceff: 8 blocks x 4 waves x 4 o's
        int w = tid >> 6, l = tid & 63;
        #pragma unroll
        for (int i = 0; i < 4; ++i) {
            int o = (blk - 32) * 16 + w * 4 + i;
            float sum = 0.f;
            #pragma unroll
            for (int it = 0; it < 7; ++it) {
                int k = l + it * 64;
                if (k < IN_DIM) {
                    float a0 = bn0_g[k] * rsqrtf(bn0_v[k] + EPS);
                    float u0 = bn0_b[k] - a0 * bn0_m[k];
                    sum += u0 * W1[o * IN_DIM + k];
                }
            }
            sum += __shfl_xor(sum, 32);
            sum += __shfl_xor(sum, 16);
            sum += __shfl_xor(sum, 8);
            sum += __shfl_xor(sum, 4);
            sum += __shfl_xor(sum, 2);
            sum += __shfl_xor(sum, 1);
            if (l == 0) {
                float a1 = bn1_g[o] * rsqrtf(bn1_v[o] + EPS);
                ceff[o] = a1 * (sum + b1[o] - bn1_m[o]) + bn1_b[o];
            }
        }
    } else {                              // c2[64] + fused constant
        if (tid < H2) {
            float a2 = bn2_g[tid] * rsqrtf(bn2_v[tid] + EPS);
            c2[tid] = a2 * (b2[tid] - bn2_m[tid]) + bn2_b[tid];
        } else if (tid == 64) {
            constv[0] = gbias[0] + bo[0] + ldb[0];
        }
    }
}

// ---------------------------------------------------------------------------
// Main fused kernel: gather + FM + linear + MLP (2 MFMA GEMMs) + combine.
// 512 blocks x 512 threads, 32 rows/block. 2 blocks/CU -> 16 waves/CU.
// ---------------------------------------------------------------------------
__global__ __launch_bounds__(NT, 4) void deepfm_main(
    const int*   __restrict__ sparse, const float* __restrict__ dense,
    const float* __restrict__ emb,    const float* __restrict__ lin,
    const float* __restrict__ ldw,
    const unsigned short* __restrict__ packB1,
    const unsigned short* __restrict__ packB2,
    const float* __restrict__ ceff, const float* __restrict__ c2w,
    const float* __restrict__ Wo,   const float* __restrict__ constv,
    float* __restrict__ out)
{
    __shared__ __align__(16) unsigned short deepS[BM][SD];
    __shared__ __align__(16) unsigned short h1S[BM][SH];
    __shared__ __align__(16) int sparseS[BM * NF];
    __shared__ float accS[BM];

    const int tid = threadIdx.x;
    const int r0  = blockIdx.x * BM;

    // Phase A: init accumulators, zero K-padding (cols 429..447), stage sparse
    if (tid < BM) accS[tid] = constv[0];
    {
        int z = tid;                        // BM*19 = 608 <= NT+96: two passes
        if (z < BM * (KPAD - IN_DIM)) {
            int row = z / (KPAD - IN_DIM), c = IN_DIM + z % (KPAD - IN_DIM);
            deepS[row][c] = 0;
        }
        z = tid + NT;
        if (z < BM * (KPAD - IN_DIM)) {
            int row = z / (KPAD - IN_DIM), c = IN_DIM + z % (KPAD - IN_DIM);
            deepS[row][c] = 0;
        }
    }
    if (tid < BM * NF / 2) {                // 416 int2 loads, coalesced
        reinterpret_cast<int2*>(sparseS)[tid] =
            reinterpret_cast<const int2*>(sparse + (size_t)r0 * NF)[tid];
    }
    __syncthreads();

    // Phase B: embedding gather (4 lanes per (row,feature); 16B each) + linear_sparse
    #pragma unroll
    for (int it = 0; it < 7; ++it) {        // 32*26*4 = 3328 tasks
        int q = tid + it * NT;
        if (q < BM * NF * 4) {
            int p = q >> 2, quarter = q & 3;
            int row = p / NF, f = p - row * NF;
            int idx = sparseS[p];
            const float* src = emb + ((size_t)f * V1 + (size_t)idx) * NE + quarter * 4;
            float4 v = *reinterpret_cast<const float4*>(src);
            ushort4 sv = { f2bf(v.x), f2bf(v.y), f2bf(v.z), f2bf(v.w) };
            *reinterpret_cast<ushort4*>(&deepS[row][f * NE + quarter * 4]) = sv;
            if (quarter == 0) {
                atomicAdd(&accS[row], lin[(size_t)f * V1 + (size_t)idx]);
            }
        }
    }
    // Phase C: dense features + linear_dense (416 tasks, single pass, coalesced)
    if (tid < BM * ND) {
        int row = tid / ND, j = tid - row * ND;
        float v = dense[(r0 + row) * ND + j];
        deepS[row][NF * NE + j] = f2bf(v);
        atomicAdd(&accS[row], v * ldw[j]);
    }
    __syncthreads();

    // Phase D: FM term — 512 = 32 rows x 16 e, single pass, shuffle-reduced
    {
        int row = tid >> 4, e = tid & 15;
        float s = 0.f, ss = 0.f;
        #pragma unroll
        for (int f = 0; f < NF; ++f) {
            float x = bf2f(deepS[row][f * NE + e]);
            s += x; ss += x * x;
        }
        float fmv = 0.5f * (s * s - ss);
        fmv += __shfl_xor(fmv, 1);
        fmv += __shfl_xor(fmv, 2);
        fmv += __shfl_xor(fmv, 4);
        fmv += __shfl_xor(fmv, 8);
        if (e == 0) atomicAdd(&accS[row], fmv);
    }

    // Phase E: GEMM1 [32 x 448] x [448 -> 128], wave w owns nblk=w (16 cols), both mblks
    const int w = tid >> 6, l = tid & 63;
    const int lr = l & 15, lq = l >> 4;

    f32x4 acc1[2] = { {0.f,0.f,0.f,0.f}, {0.f,0.f,0.f,0.f} };
    const short8* pB1 = reinterpret_cast<const short8*>(packB1);
    #pragma unroll
    for (int ks = 0; ks < KPAD / 32; ++ks) {
        short8 aF0 = *reinterpret_cast<const short8*>(&deepS[lr     ][ks * 32 + lq * 8]);
        short8 aF1 = *reinterpret_cast<const short8*>(&deepS[16 + lr][ks * 32 + lq * 8]);
        short8 bF  = pB1[((size_t)w * 14 + ks) * 64 + l];
        acc1[0] = __builtin_amdgcn_mfma_f32_16x16x32_bf16(aF0, bF, acc1[0], 0, 0, 0);
        acc1[1] = __builtin_amdgcn_mfma_f32_16x16x32_bf16(aF1, bF, acc1[1], 0, 0, 0);
    }
    // Epilogue 1: +ceff, relu, -> bf16 LDS (C/D layout: col=l&15, row=lq*4+r)
    {
        int col = w * 16 + lr;
        float ce = ceff[col];
        #pragma unroll
        for (int mb = 0; mb < 2; ++mb) {
            #pragma unroll
            for (int r = 0; r < 4; ++r) {
                float h = fmaxf(acc1[mb][r] + ce, 0.f);
                h1S[mb * 16 + lq * 4 + r][col] = f2bf(h);
            }
        }
    }
    __syncthreads();

    // Phase F: GEMM2 [32 x 128] x [128 -> 64]; wave: mblk2 = w>>2, nb2 = w&3
    const int mblk2 = w >> 2, nb2 = w & 3;
    f32x4 acc2 = { 0.f, 0.f, 0.f, 0.f };
    const short8* pB2 = reinterpret_cast<const short8*>(packB2);
    #pragma unroll
    for (int ks = 0; ks < 4; ++ks) {
        short8 aF = *reinterpret_cast<const short8*>(&h1S[mblk2 * 16 + lr][ks * 32 + lq * 8]);
        short8 bF = pB2[((size_t)nb2 * 4 + ks) * 64 + l];
        acc2 = __builtin_amdgcn_mfma_f32_16x16x32_bf16(aF, bF, acc2, 0, 0, 0);
    }
    // Epilogue 2: +c2, relu, dot Wo, reduce over 16 col-lanes, add to accS
    {
        int col = nb2 * 16 + lr;
        float cv = c2w[col], wv = Wo[col];
        float part[4];
        #pragma unroll
        for (int r = 0; r < 4; ++r)
            part[r] = fmaxf(acc2[r] + cv, 0.f) * wv;
        #pragma unroll
        for (int r = 0; r < 4; ++r) {
            part[r] += __shfl_xor(part[r], 1);
            part[r] += __shfl_xor(part[r], 2);
            part[r] += __shfl_xor(part[r], 4);
            part[r] += __shfl_xor(part[r], 8);
        }
        if (lr == 0) {
            #pragma unroll
            for (int r = 0; r < 4; ++r)
                atomicAdd(&accS[mblk2 * 16 + lq * 4 + r], part[r]);
        }
    }
    __syncthreads();

    // Phase G: write outputs
    if (tid < BM) out[r0 + tid] = accS[tid];
}

extern "C" void kernel_launch(void* const* d_in, const int* in_sizes, int n_in,
                              void* d_out, int out_size, void* d_ws, size_t ws_size,
                              hipStream_t stream) {
    const int*   sparse = (const int*)d_in[0];
    const float* dense  = (const float*)d_in[1];
    const float* emb    = (const float*)d_in[2];
    const float* lin    = (const float*)d_in[3];
    const float* ldw    = (const float*)d_in[4];
    const float* ldb    = (const float*)d_in[5];
    const float* bn0g = (const float*)d_in[6],  *bn0b = (const float*)d_in[7];
    const float* bn0m = (const float*)d_in[8],  *bn0v = (const float*)d_in[9];
    const float* W1   = (const float*)d_in[10], *b1   = (const float*)d_in[11];
    const float* bn1g = (const float*)d_in[12], *bn1b = (const float*)d_in[13];
    const float* bn1m = (const float*)d_in[14], *bn1v = (const float*)d_in[15];
    const float* W2   = (const float*)d_in[16], *b2   = (const float*)d_in[17];
    const float* bn2g = (const float*)d_in[18], *bn2b = (const float*)d_in[19];
    const float* bn2m = (const float*)d_in[20], *bn2v = (const float*)d_in[21];
    const float* Wo   = (const float*)d_in[22], *bo   = (const float*)d_in[23];
    const float* gbias = (const float*)d_in[24];

    char* ws = (char*)d_ws;
    unsigned short* packB1 = (unsigned short*)ws;              // 114688 B
    unsigned short* packB2 = (unsigned short*)(ws + 114688);   //  16384 B
    float* ceff   = (float*)(ws + 131072);                     //    512 B
    float* c2     = (float*)(ws + 131584);                     //    256 B
    float* constv = (float*)(ws + 131840);                     //      4 B

    prep_kernel<<<41, 256, 0, stream>>>(
        bn0g, bn0b, bn0m, bn0v, W1, b1, bn1g, bn1b, bn1m, bn1v,
        W2, b2, bn2g, bn2b, bn2m, bn2v, bo, gbias, ldb,
        packB1, packB2, ceff, c2, constv);

    deepfm_main<<<BATCH / BM, NT, 0, stream>>>(
        sparse, dense, emb, lin, ldw, packB1, packB2, ceff, c2, Wo, constv,
        (float*)d_out);
}

// Round 3
// 272.126 us; speedup vs baseline: 1.1362x; 1.0013x over previous
//
#include <hip/hip_runtime.h>

#define BATCH  16384
#define NF     26
#define ND     13
#define NE     16
#define V1     100001
#define H1     128
#define H2     64
#define IN_DIM 429     // NF*NE + ND
#define KPAD   448     // 14 * 32
#define EPS    1e-5f

#define BM     32      // rows per block
#define NT     512     // threads per block (8 waves)
#define SD     456     // deepS row stride (ushort): 912B/row, %16==0, 228 dwords %32 = 4
#define SH     136     // h1S row stride (ushort)

typedef __attribute__((ext_vector_type(8))) short short8;
typedef __attribute__((ext_vector_type(4))) float f32x4;

static __device__ __forceinline__ unsigned short f2bf(float x) {
    unsigned int u = __float_as_uint(x);
    unsigned int r = (u + 0x7FFFu + ((u >> 16) & 1u)) >> 16;   // RNE
    return (unsigned short)r;
}
static __device__ __forceinline__ float bf2f(unsigned short s) {
    return __uint_as_float(((unsigned int)s) << 16);
}

// ---------------------------------------------------------------------------
// Prep kernel: fold BN into effective weights, pack into MFMA B-fragment order.
// packB1: [nblk(8)][ks(14)][lane(64)][8 bf16]  B[k][col], col=16*nblk+(l&15), k=32*ks+(l>>4)*8+j
// packB2: [nblk(4)][ks(4)] [lane(64)][8 bf16]
// Grid: 0-27 packB1, 28-31 packB2, 32-39 ceff, 40 c2+const.
// ---------------------------------------------------------------------------
__global__ __launch_bounds__(256) void prep_kernel(
    const float* __restrict__ bn0_g, const float* __restrict__ bn0_b,
    const float* __restrict__ bn0_m, const float* __restrict__ bn0_v,
    const float* __restrict__ W1,    const float* __restrict__ b1,
    const float* __restrict__ bn1_g, const float* __restrict__ bn1_b,
    const float* __restrict__ bn1_m, const float* __restrict__ bn1_v,
    const float* __restrict__ W2,    const float* __restrict__ b2,
    const float* __restrict__ bn2_g, const float* __restrict__ bn2_b,
    const float* __restrict__ bn2_m, const float* __restrict__ bn2_v,
    const float* __restrict__ bo,    const float* __restrict__ gbias,
    const float* __restrict__ ldb,
    unsigned short* __restrict__ packB1, unsigned short* __restrict__ packB2,
    float* __restrict__ ceff, float* __restrict__ c2, float* __restrict__ constv)
{
    const int blk = blockIdx.x, tid = threadIdx.x;

    if (blk < 28) {                       // packB1: 7168 threads
        int t    = blk * 256 + tid;
        int nblk = t / (14 * 64);
        int rem  = t % (14 * 64);
        int ks   = rem >> 6;
        int l    = rem & 63;
        int col  = nblk * 16 + (l & 15);
        float a1 = bn1_g[col] * rsqrtf(bn1_v[col] + EPS);
        int k0   = ks * 32 + ((l >> 4) << 3);
        union { short8 v; unsigned short u[8]; } tmp;
        #pragma unroll
        for (int j = 0; j < 8; ++j) {
            int k = k0 + j;
            float v = 0.f;
            if (k < IN_DIM) {
                float a0 = bn0_g[k] * rsqrtf(bn0_v[k] + EPS);
                v = W1[col * IN_DIM + k] * a0 * a1;
            }
            tmp.u[j] = f2bf(v);
        }
        *reinterpret_cast<short8*>(packB1 + (size_t)t * 8) = tmp.v;
    } else if (blk < 32) {                // packB2: 1024 threads
        int t    = (blk - 28) * 256 + tid;
        int nblk = t >> 8;
        int rem  = t & 255;
        int ks   = rem >> 6;
        int l    = rem & 63;
        int col  = nblk * 16 + (l & 15);
        float a2 = bn2_g[col] * rsqrtf(bn2_v[col] + EPS);
        int k0   = ks * 32 + ((l >> 4) << 3);
        union { short8 v; unsigned short u[8]; } tmp;
        #pragma unroll
        for (int j = 0; j < 8; ++j) {
            int k = k0 + j;
            tmp.u[j] = f2bf(W2[col * H1 + k] * a2);
        }
        *reinterpret_cast<short8*>(packB2 + (size_t)t * 8) = tmp.v;
    } else if (blk < 40) {                // ceff: 8 blocks x 4 waves x 4 o's
        int w = tid >> 6, l = tid & 63;
        #pragma unroll
        for (int i = 0; i < 4; ++i) {
            int o = (blk - 32) * 16 + w * 4 + i;
            float sum = 0.f;
            #pragma unroll
            for (int it = 0; it < 7; ++it) {
                int k = l + it * 64;
                if (k < IN_DIM) {
                    float a0 = bn0_g[k] * rsqrtf(bn0_v[k] + EPS);
                    float u0 = bn0_b[k] - a0 * bn0_m[k];
                    sum += u0 * W1[o * IN_DIM + k];
                }
            }
            sum += __shfl_xor(sum, 32);
            sum += __shfl_xor(sum, 16);
            sum += __shfl_xor(sum, 8);
            sum += __shfl_xor(sum, 4);
            sum += __shfl_xor(sum, 2);
            sum += __shfl_xor(sum, 1);
            if (l == 0) {
                float a1 = bn1_g[o] * rsqrtf(bn1_v[o] + EPS);
                ceff[o] = a1 * (sum + b1[o] - bn1_m[o]) + bn1_b[o];
            }
        }
    } else {                              // c2[64] + fused constant
        if (tid < H2) {
            float a2 = bn2_g[tid] * rsqrtf(bn2_v[tid] + EPS);
            c2[tid] = a2 * (b2[tid] - bn2_m[tid]) + bn2_b[tid];
        } else if (tid == 64) {
            constv[0] = gbias[0] + bo[0] + ldb[0];
        }
    }
}

// ---------------------------------------------------------------------------
// Main fused kernel: gather + FM + linear + MLP (2 MFMA GEMMs) + combine.
// 512 blocks x 512 threads, 32 rows/block. Target 3 blocks/CU (24 waves).
// No entry barrier: gather loads issue from instruction 0; linear terms go
// through plain LDS arrays reduced in Phase D (no LDS atomics, no accS init).
// ---------------------------------------------------------------------------
__global__ __launch_bounds__(NT, 6) void deepfm_main(
    const int*   __restrict__ sparse, const float* __restrict__ dense,
    const float* __restrict__ emb,    const float* __restrict__ lin,
    const float* __restrict__ ldw,
    const unsigned short* __restrict__ packB1,
    const unsigned short* __restrict__ packB2,
    const float* __restrict__ ceff, const float* __restrict__ c2w,
    const float* __restrict__ Wo,   const float* __restrict__ constv,
    float* __restrict__ out)
{
    __shared__ __align__(16) unsigned short deepS[BM][SD];
    __shared__ __align__(16) unsigned short h1S[BM][SH];
    __shared__ float linS[BM][NF];     // raw lin-table values per (row,f)
    __shared__ float dlinS[BM][ND];    // dense * ldw per (row,j)
    __shared__ float accS[BM];

    const int tid = threadIdx.x;
    const int r0  = blockIdx.x * BM;

    // Phase B: embedding gather — first instructions of the kernel.
    // 3328 tasks: 4 lanes per (row,feature), 16B each; quarter==0 lane also
    // fetches the lin-table scalar into linS (no atomic).
    #pragma unroll
    for (int it = 0; it < 7; ++it) {
        int q = tid + it * NT;
        if (q < BM * NF * 4) {
            int p = q >> 2, quarter = q & 3;
            int row = p / NF, f = p - row * NF;
            int idx = sparse[r0 * NF + p];          // 4 lanes same addr: merged
            const float* src = emb + ((size_t)f * V1 + (size_t)idx) * NE + quarter * 4;
            float4 v = *reinterpret_cast<const float4*>(src);
            ushort4 sv = { f2bf(v.x), f2bf(v.y), f2bf(v.z), f2bf(v.w) };
            *reinterpret_cast<ushort4*>(&deepS[row][f * NE + quarter * 4]) = sv;
            if (quarter == 0) {
                linS[row][f] = lin[(size_t)f * V1 + (size_t)idx];
            }
        }
    }
    // Zero K-padding (cols 429..447): 608 tasks
    {
        int z = tid;
        if (z < BM * (KPAD - IN_DIM)) {
            int row = z / (KPAD - IN_DIM), c = IN_DIM + z % (KPAD - IN_DIM);
            deepS[row][c] = 0;
        }
        z = tid + NT;
        if (z < BM * (KPAD - IN_DIM)) {
            int row = z / (KPAD - IN_DIM), c = IN_DIM + z % (KPAD - IN_DIM);
            deepS[row][c] = 0;
        }
    }
    // Phase C: dense features (416 tasks, coalesced f32)
    if (tid < BM * ND) {
        int row = tid / ND, j = tid - row * ND;
        float v = dense[(r0 + row) * ND + j];
        deepS[row][NF * NE + j] = f2bf(v);
        dlinS[row][j] = v * ldw[j];
    }
    __syncthreads();

    // Phase D: FM + linear terms, one shuffle tree. 512 = 32 rows x 16 lanes.
    {
        int row = tid >> 4, e = tid & 15;
        float s = 0.f, ss = 0.f;
        #pragma unroll
        for (int f = 0; f < NF; ++f) {
            float x = bf2f(deepS[row][f * NE + e]);
            s += x; ss += x * x;
        }
        float t = 0.5f * (s * s - ss);
        t += linS[row][e];
        if (e < NF - 16) t += linS[row][16 + e];
        if (e < ND)      t += dlinS[row][e];
        t += __shfl_xor(t, 1);
        t += __shfl_xor(t, 2);
        t += __shfl_xor(t, 4);
        t += __shfl_xor(t, 8);
        if (e == 0) accS[row] = constv[0] + t;
    }

    // Phase E: GEMM1 [32 x 448] x [448 -> 128]; wave w owns 16 cols, both mblks
    const int w = tid >> 6, l = tid & 63;
    const int lr = l & 15, lq = l >> 4;

    f32x4 acc1[2] = { {0.f,0.f,0.f,0.f}, {0.f,0.f,0.f,0.f} };
    const short8* pB1 = reinterpret_cast<const short8*>(packB1);
    #pragma unroll
    for (int ks = 0; ks < KPAD / 32; ++ks) {
        short8 aF0 = *reinterpret_cast<const short8*>(&deepS[lr     ][ks * 32 + lq * 8]);
        short8 aF1 = *reinterpret_cast<const short8*>(&deepS[16 + lr][ks * 32 + lq * 8]);
        short8 bF  = pB1[((size_t)w * 14 + ks) * 64 + l];
        acc1[0] = __builtin_amdgcn_mfma_f32_16x16x32_bf16(aF0, bF, acc1[0], 0, 0, 0);
        acc1[1] = __builtin_amdgcn_mfma_f32_16x16x32_bf16(aF1, bF, acc1[1], 0, 0, 0);
    }
    // Epilogue 1: +ceff, relu, -> bf16 LDS (C/D layout: col=l&15, row=lq*4+r)
    {
        int col = w * 16 + lr;
        float ce = ceff[col];
        #pragma unroll
        for (int mb = 0; mb < 2; ++mb) {
            #pragma unroll
            for (int r = 0; r < 4; ++r) {
                float h = fmaxf(acc1[mb][r] + ce, 0.f);
                h1S[mb * 16 + lq * 4 + r][col] = f2bf(h);
            }
        }
    }
    __syncthreads();

    // Phase F: GEMM2 [32 x 128] x [128 -> 64]; wave: mblk2 = w>>2, nb2 = w&3
    const int mblk2 = w >> 2, nb2 = w & 3;
    f32x4 acc2 = { 0.f, 0.f, 0.f, 0.f };
    const short8* pB2 = reinterpret_cast<const short8*>(packB2);
    #pragma unroll
    for (int ks = 0; ks < 4; ++ks) {
        short8 aF = *reinterpret_cast<const short8*>(&h1S[mblk2 * 16 + lr][ks * 32 + lq * 8]);
        short8 bF = pB2[((size_t)nb2 * 4 + ks) * 64 + l];
        acc2 = __builtin_amdgcn_mfma_f32_16x16x32_bf16(aF, bF, acc2, 0, 0, 0);
    }
    // Epilogue 2: +c2, relu, dot Wo, reduce over 16 col-lanes, add to accS
    {
        int col = nb2 * 16 + lr;
        float cv = c2w[col], wv = Wo[col];
        float part[4];
        #pragma unroll
        for (int r = 0; r < 4; ++r)
            part[r] = fmaxf(acc2[r] + cv, 0.f) * wv;
        #pragma unroll
        for (int r = 0; r < 4; ++r) {
            part[r] += __shfl_xor(part[r], 1);
            part[r] += __shfl_xor(part[r], 2);
            part[r] += __shfl_xor(part[r], 4);
            part[r] += __shfl_xor(part[r], 8);
        }
        if (lr == 0) {
            #pragma unroll
            for (int r = 0; r < 4; ++r)
                atomicAdd(&accS[mblk2 * 16 + lq * 4 + r], part[r]);
        }
    }
    __syncthreads();

    // Phase G: write outputs
    if (tid < BM) out[r0 + tid] = accS[tid];
}

extern "C" void kernel_launch(void* const* d_in, const int* in_sizes, int n_in,
                              void* d_out, int out_size, void* d_ws, size_t ws_size,
                              hipStream_t stream) {
    const int*   sparse = (const int*)d_in[0];
    const float* dense  = (const float*)d_in[1];
    const float* emb    = (const float*)d_in[2];
    const float* lin    = (const float*)d_in[3];
    const float* ldw    = (const float*)d_in[4];
    const float* ldb    = (const float*)d_in[5];
    const float* bn0g = (const float*)d_in[6],  *bn0b = (const float*)d_in[7];
    const float* bn0m = (const float*)d_in[8],  *bn0v = (const float*)d_in[9];
    const float* W1   = (const float*)d_in[10], *b1   = (const float*)d_in[11];
    const float* bn1g = (const float*)d_in[12], *bn1b = (const float*)d_in[13];
    const float* bn1m = (const float*)d_in[14], *bn1v = (const float*)d_in[15];
    const float* W2   = (const float*)d_in[16], *b2   = (const float*)d_in[17];
    const float* bn2g = (const float*)d_in[18], *bn2b = (const float*)d_in[19];
    const float* bn2m = (const float*)d_in[20], *bn2v = (const float*)d_in[21];
    const float* Wo   = (const float*)d_in[22], *bo   = (const float*)d_in[23];
    const float* gbias = (const float*)d_in[24];

    char* ws = (char*)d_ws;
    unsigned short* packB1 = (unsigned short*)ws;              // 114688 B
    unsigned short* packB2 = (unsigned short*)(ws + 114688);   //  16384 B
    float* ceff   = (float*)(ws + 131072);                     //    512 B
    float* c2     = (float*)(ws + 131584);                     //    256 B
    float* constv = (float*)(ws + 131840);                     //      4 B

    prep_kernel<<<41, 256, 0, stream>>>(
        bn0g, bn0b, bn0m, bn0v, W1, b1, bn1g, bn1b, bn1m, bn1v,
        W2, b2, bn2g, bn2b, bn2m, bn2v, bo, gbias, ldb,
        packB1, packB2, ceff, c2, constv);

    deepfm_main<<<BATCH / BM, NT, 0, stream>>>(
        sparse, dense, emb, lin, ldw, packB1, packB2, ceff, c2, Wo, constv,
        (float*)d_out);
}

// Round 4
// 272.117 us; speedup vs baseline: 1.1362x; 1.0000x over previous
//
#include <hip/hip_runtime.h>

#define BATCH  16384
#define NF     26
#define ND     13
#define NE     16
#define V1     100001
#define H1     128
#define H2     64
#define IN_DIM 429     // NF*NE + ND
#define KPAD   448     // 14 * 32
#define EPS    1e-5f

#define BM     16      // rows per block
#define NT     256     // threads per block (4 waves)
#define SD     456     // deepS row stride (ushort): 912B/row, %16==0
#define SH     136     // h1S row stride (ushort)

typedef __attribute__((ext_vector_type(8))) short short8;
typedef __attribute__((ext_vector_type(4))) float f32x4;

static __device__ __forceinline__ unsigned short f2bf(float x) {
    unsigned int u = __float_as_uint(x);
    unsigned int r = (u + 0x7FFFu + ((u >> 16) & 1u)) >> 16;   // RNE
    return (unsigned short)r;
}
static __device__ __forceinline__ float bf2f(unsigned short s) {
    return __uint_as_float(((unsigned int)s) << 16);
}

// ---------------------------------------------------------------------------
// Prep kernel: fold BN into effective weights, pack into MFMA B-fragment order.
// packB1: [nblk(8)][ks(14)][lane(64)][8 bf16]  B[k][col], col=16*nblk+(l&15), k=32*ks+(l>>4)*8+j
// packB2: [nblk(4)][ks(4)] [lane(64)][8 bf16]
// Grid: 0-27 packB1, 28-31 packB2, 32-39 ceff, 40 c2+const.
// ---------------------------------------------------------------------------
__global__ __launch_bounds__(256) void prep_kernel(
    const float* __restrict__ bn0_g, const float* __restrict__ bn0_b,
    const float* __restrict__ bn0_m, const float* __restrict__ bn0_v,
    const float* __restrict__ W1,    const float* __restrict__ b1,
    const float* __restrict__ bn1_g, const float* __restrict__ bn1_b,
    const float* __restrict__ bn1_m, const float* __restrict__ bn1_v,
    const float* __restrict__ W2,    const float* __restrict__ b2,
    const float* __restrict__ bn2_g, const float* __restrict__ bn2_b,
    const float* __restrict__ bn2_m, const float* __restrict__ bn2_v,
    const float* __restrict__ bo,    const float* __restrict__ gbias,
    const float* __restrict__ ldb,
    unsigned short* __restrict__ packB1, unsigned short* __restrict__ packB2,
    float* __restrict__ ceff, float* __restrict__ c2, float* __restrict__ constv)
{
    const int blk = blockIdx.x, tid = threadIdx.x;

    if (blk < 28) {                       // packB1: 7168 threads
        int t    = blk * 256 + tid;
        int nblk = t / (14 * 64);
        int rem  = t % (14 * 64);
        int ks   = rem >> 6;
        int l    = rem & 63;
        int col  = nblk * 16 + (l & 15);
        float a1 = bn1_g[col] * rsqrtf(bn1_v[col] + EPS);
        int k0   = ks * 32 + ((l >> 4) << 3);
        union { short8 v; unsigned short u[8]; } tmp;
        #pragma unroll
        for (int j = 0; j < 8; ++j) {
            int k = k0 + j;
            float v = 0.f;
            if (k < IN_DIM) {
                float a0 = bn0_g[k] * rsqrtf(bn0_v[k] + EPS);
                v = W1[col * IN_DIM + k] * a0 * a1;
            }
            tmp.u[j] = f2bf(v);
        }
        *reinterpret_cast<short8*>(packB1 + (size_t)t * 8) = tmp.v;
    } else if (blk < 32) {                // packB2: 1024 threads
        int t    = (blk - 28) * 256 + tid;
        int nblk = t >> 8;
        int rem  = t & 255;
        int ks   = rem >> 6;
        int l    = rem & 63;
        int col  = nblk * 16 + (l & 15);
        float a2 = bn2_g[col] * rsqrtf(bn2_v[col] + EPS);
        int k0   = ks * 32 + ((l >> 4) << 3);
        union { short8 v; unsigned short u[8]; } tmp;
        #pragma unroll
        for (int j = 0; j < 8; ++j) {
            int k = k0 + j;
            tmp.u[j] = f2bf(W2[col * H1 + k] * a2);
        }
        *reinterpret_cast<short8*>(packB2 + (size_t)t * 8) = tmp.v;
    } else if (blk < 40) {                // ceff: 8 blocks x 4 waves x 4 o's
        int w = tid >> 6, l = tid & 63;
        #pragma unroll
        for (int i = 0; i < 4; ++i) {
            int o = (blk - 32) * 16 + w * 4 + i;
            float sum = 0.f;
            #pragma unroll
            for (int it = 0; it < 7; ++it) {
                int k = l + it * 64;
                if (k < IN_DIM) {
                    float a0 = bn0_g[k] * rsqrtf(bn0_v[k] + EPS);
                    float u0 = bn0_b[k] - a0 * bn0_m[k];
                    sum += u0 * W1[o * IN_DIM + k];
                }
            }
            sum += __shfl_xor(sum, 32);
            sum += __shfl_xor(sum, 16);
            sum += __shfl_xor(sum, 8);
            sum += __shfl_xor(sum, 4);
            sum += __shfl_xor(sum, 2);
            sum += __shfl_xor(sum, 1);
            if (l == 0) {
                float a1 = bn1_g[o] * rsqrtf(bn1_v[o] + EPS);
                ceff[o] = a1 * (sum + b1[o] - bn1_m[o]) + bn1_b[o];
            }
        }
    } else {                              // c2[64] + fused constant
        if (tid < H2) {
            float a2 = bn2_g[tid] * rsqrtf(bn2_v[tid] + EPS);
            c2[tid] = a2 * (b2[tid] - bn2_m[tid]) + bn2_b[tid];
        } else if (tid == 64) {
            constv[0] = gbias[0] + bo[0] + ldb[0];
        }
    }
}

// ---------------------------------------------------------------------------
// Main fused kernel: gather + FM + linear + MLP (2 MFMA GEMMs) + combine.
// 1024 blocks x 256 threads, 16 rows/block. ~21.5 KB LDS -> 6 blocks/CU
// (24 waves/CU) with __launch_bounds__(256,6); finer block-level overlap of
// gather (latency-bound) and MFMA (compute) phases across blocks.
// ---------------------------------------------------------------------------
__global__ __launch_bounds__(NT, 6) void deepfm_main(
    const int*   __restrict__ sparse, const float* __restrict__ dense,
    const float* __restrict__ emb,    const float* __restrict__ lin,
    const float* __restrict__ ldw,
    const unsigned short* __restrict__ packB1,
    const unsigned short* __restrict__ packB2,
    const float* __restrict__ ceff, const float* __restrict__ c2w,
    const float* __restrict__ Wo,   const float* __restrict__ constv,
    float* __restrict__ out)
{
    __shared__ __align__(16) unsigned short deepS[BM][SD];
    __shared__ __align__(16) unsigned short h1S[BM][SH];
    __shared__ float linS[BM][NF];     // raw lin-table values per (row,f)
    __shared__ float dlinS[BM][ND];    // dense * ldw per (row,j)
    __shared__ float accS[BM];

    const int tid = threadIdx.x;
    const int r0  = blockIdx.x * BM;

    // Phase B: embedding gather — first instructions of the kernel.
    // 1664 tasks: 4 lanes per (row,feature), 16B each; quarter==0 lane also
    // fetches the lin-table scalar into linS.
    #pragma unroll
    for (int it = 0; it < 7; ++it) {
        int q = tid + it * NT;
        if (q < BM * NF * 4) {
            int p = q >> 2, quarter = q & 3;
            int row = p / NF, f = p - row * NF;
            int idx = sparse[r0 * NF + p];          // 4 lanes same addr: merged
            const float* src = emb + ((size_t)f * V1 + (size_t)idx) * NE + quarter * 4;
            float4 v = *reinterpret_cast<const float4*>(src);
            ushort4 sv = { f2bf(v.x), f2bf(v.y), f2bf(v.z), f2bf(v.w) };
            *reinterpret_cast<ushort4*>(&deepS[row][f * NE + quarter * 4]) = sv;
            if (quarter == 0) {
                linS[row][f] = lin[(size_t)f * V1 + (size_t)idx];
            }
        }
    }
    // Zero K-padding (cols 429..447): 304 tasks
    {
        int z = tid;
        if (z < BM * (KPAD - IN_DIM)) {
            int row = z / (KPAD - IN_DIM), c = IN_DIM + z % (KPAD - IN_DIM);
            deepS[row][c] = 0;
        }
        z = tid + NT;
        if (z < BM * (KPAD - IN_DIM)) {
            int row = z / (KPAD - IN_DIM), c = IN_DIM + z % (KPAD - IN_DIM);
            deepS[row][c] = 0;
        }
    }
    // Phase C: dense features (208 tasks, coalesced f32)
    if (tid < BM * ND) {
        int row = tid / ND, j = tid - row * ND;
        float v = dense[(r0 + row) * ND + j];
        deepS[row][NF * NE + j] = f2bf(v);
        dlinS[row][j] = v * ldw[j];
    }
    __syncthreads();

    // Phase D: FM + linear terms, one shuffle tree. 256 = 16 rows x 16 lanes.
    {
        int row = tid >> 4, e = tid & 15;
        float s = 0.f, ss = 0.f;
        #pragma unroll
        for (int f = 0; f < NF; ++f) {
            float x = bf2f(deepS[row][f * NE + e]);
            s += x; ss += x * x;
        }
        float t = 0.5f * (s * s - ss);
        t += linS[row][e];
        if (e < NF - 16) t += linS[row][16 + e];
        if (e < ND)      t += dlinS[row][e];
        t += __shfl_xor(t, 1);
        t += __shfl_xor(t, 2);
        t += __shfl_xor(t, 4);
        t += __shfl_xor(t, 8);
        if (e == 0) accS[row] = constv[0] + t;
    }

    // Phase E: GEMM1 [16 x 448] x [448 -> 128]; wave w owns nblks {2w, 2w+1}
    const int w = tid >> 6, l = tid & 63;
    const int lr = l & 15, lq = l >> 4;

    f32x4 acc1[2] = { {0.f,0.f,0.f,0.f}, {0.f,0.f,0.f,0.f} };
    const short8* pB1 = reinterpret_cast<const short8*>(packB1);
    #pragma unroll
    for (int ks = 0; ks < KPAD / 32; ++ks) {
        short8 aF  = *reinterpret_cast<const short8*>(&deepS[lr][ks * 32 + lq * 8]);
        short8 bF0 = pB1[((size_t)(2 * w    ) * 14 + ks) * 64 + l];
        short8 bF1 = pB1[((size_t)(2 * w + 1) * 14 + ks) * 64 + l];
        acc1[0] = __builtin_amdgcn_mfma_f32_16x16x32_bf16(aF, bF0, acc1[0], 0, 0, 0);
        acc1[1] = __builtin_amdgcn_mfma_f32_16x16x32_bf16(aF, bF1, acc1[1], 0, 0, 0);
    }
    // Epilogue 1: +ceff, relu, -> bf16 LDS (C/D layout: col=l&15, row=lq*4+r)
    {
        #pragma unroll
        for (int nb = 0; nb < 2; ++nb) {
            int col = (2 * w + nb) * 16 + lr;
            float ce = ceff[col];
            #pragma unroll
            for (int r = 0; r < 4; ++r) {
                float h = fmaxf(acc1[nb][r] + ce, 0.f);
                h1S[lq * 4 + r][col] = f2bf(h);
            }
        }
    }
    __syncthreads();

    // Phase F: GEMM2 [16 x 128] x [128 -> 64]; wave w -> nblk w
    f32x4 acc2 = { 0.f, 0.f, 0.f, 0.f };
    const short8* pB2 = reinterpret_cast<const short8*>(packB2);
    #pragma unroll
    for (int ks = 0; ks < 4; ++ks) {
        short8 aF = *reinterpret_cast<const short8*>(&h1S[lr][ks * 32 + lq * 8]);
        short8 bF = pB2[((size_t)w * 4 + ks) * 64 + l];
        acc2 = __builtin_amdgcn_mfma_f32_16x16x32_bf16(aF, bF, acc2, 0, 0, 0);
    }
    // Epilogue 2: +c2, relu, dot Wo, reduce over 16 col-lanes, add to accS
    {
        int col = w * 16 + lr;
        float cv = c2w[col], wv = Wo[col];
        float part[4];
        #pragma unroll
        for (int r = 0; r < 4; ++r)
            part[r] = fmaxf(acc2[r] + cv, 0.f) * wv;
        #pragma unroll
        for (int r = 0; r < 4; ++r) {
            part[r] += __shfl_xor(part[r], 1);
            part[r] += __shfl_xor(part[r], 2);
            part[r] += __shfl_xor(part[r], 4);
            part[r] += __shfl_xor(part[r], 8);
        }
        if (lr == 0) {
            #pragma unroll
            for (int r = 0; r < 4; ++r)
                atomicAdd(&accS[lq * 4 + r], part[r]);
        }
    }
    __syncthreads();

    // Phase G: write outputs
    if (tid < BM) out[r0 + tid] = accS[tid];
}

extern "C" void kernel_launch(void* const* d_in, const int* in_sizes, int n_in,
                              void* d_out, int out_size, void* d_ws, size_t ws_size,
                              hipStream_t stream) {
    const int*   sparse = (const int*)d_in[0];
    const float* dense  = (const float*)d_in[1];
    const float* emb    = (const float*)d_in[2];
    const float* lin    = (const float*)d_in[3];
    const float* ldw    = (const float*)d_in[4];
    const float* ldb    = (const float*)d_in[5];
    const float* bn0g = (const float*)d_in[6],  *bn0b = (const float*)d_in[7];
    const float* bn0m = (const float*)d_in[8],  *bn0v = (const float*)d_in[9];
    const float* W1   = (const float*)d_in[10], *b1   = (const float*)d_in[11];
    const float* bn1g = (const float*)d_in[12], *bn1b = (const float*)d_in[13];
    const float* bn1m = (const float*)d_in[14], *bn1v = (const float*)d_in[15];
    const float* W2   = (const float*)d_in[16], *b2   = (const float*)d_in[17];
    const float* bn2g = (const float*)d_in[18], *bn2b = (const float*)d_in[19];
    const float* bn2m = (const float*)d_in[20], *bn2v = (const float*)d_in[21];
    const float* Wo   = (const float*)d_in[22], *bo   = (const float*)d_in[23];
    const float* gbias = (const float*)d_in[24];

    char* ws = (char*)d_ws;
    unsigned short* packB1 = (unsigned short*)ws;              // 114688 B
    unsigned short* packB2 = (unsigned short*)(ws + 114688);   //  16384 B
    float* ceff   = (float*)(ws + 131072);                     //    512 B
    float* c2     = (float*)(ws + 131584);                     //    256 B
    float* constv = (float*)(ws + 131840);                     //      4 B

    prep_kernel<<<41, 256, 0, stream>>>(
        bn0g, bn0b, bn0m, bn0v, W1, b1, bn1g, bn1b, bn1m, bn1v,
        W2, b2, bn2g, bn2b, bn2m, bn2v, bo, gbias, ldb,
        packB1, packB2, ceff, c2, constv);

    deepfm_main<<<BATCH / BM, NT, 0, stream>>>(
        sparse, dense, emb, lin, ldw, packB1, packB2, ceff, c2, Wo, constv,
        (float*)d_out);
}